// Round 2
// baseline (591.127 us; speedup 1.0000x reference)
//
#include <hip/hip_runtime.h>

typedef unsigned short u16;
typedef short bfrag __attribute__((ext_vector_type(8)));   // 8 bf16 (4 VGPRs) for MFMA A/B
typedef float facc  __attribute__((ext_vector_type(4)));   // 4 fp32 accumulator

__device__ __forceinline__ float bf2f(u16 u) {
    union { unsigned int i; float f; } v; v.i = ((unsigned int)u) << 16; return v.f;
}
__device__ __forceinline__ u16 f2bf(float f) {
    union { float f; unsigned int i; } v; v.f = f;
    unsigned int r = v.i + 0x7FFFu + ((v.i >> 16) & 1u);
    return (u16)(r >> 16);
}

__device__ __forceinline__ u16 ld_bf(const float* p) { return f2bf(*p); }
__device__ __forceinline__ u16 ld_bf(const u16* p)   { return *p; }

__device__ __forceinline__ void store_out(u16* p, float v)   { *p = f2bf(v); }
__device__ __forceinline__ void store_out(float* p, float v) { *p = v; }

// ---------------------------------------------------------------------------
// fp32 -> bf16 elementwise convert (for weight matrices)
// ---------------------------------------------------------------------------
__global__ void cvt_k(const float* __restrict__ src, u16* __restrict__ dst, int n) {
    int i = blockIdx.x * blockDim.x + threadIdx.x;
    if (i < n) dst[i] = f2bf(src[i]);
}

// ---------------------------------------------------------------------------
// Transpose (+ optional fp32->bf16): dst[C][R] = src[R][C], per batch.
// Grid (C/64, R/64, B), block (64,8)
// ---------------------------------------------------------------------------
template <typename SrcT>
__global__ void transpose_k(const SrcT* __restrict__ src, u16* __restrict__ dst,
                            int R, int C, long sStride, long dStride) {
    __shared__ u16 tile[64][65];
    const int b  = blockIdx.z;
    const int c0 = blockIdx.x * 64;
    const int r0 = blockIdx.y * 64;
    const int x  = threadIdx.x;   // 0..63
    const int y0 = threadIdx.y;   // 0..7
    const SrcT* s = src + (size_t)b * sStride;
    for (int i = 0; i < 8; ++i) {
        int r = y0 + i * 8;
        tile[r][x] = ld_bf(&s[(size_t)(r0 + r) * C + c0 + x]);
    }
    __syncthreads();
    u16* d = dst + (size_t)b * dStride;
    for (int i = 0; i < 8; ++i) {
        int c = y0 + i * 8;
        d[(size_t)(c0 + c) * R + r0 + x] = tile[x][c];
    }
}

// ---------------------------------------------------------------------------
// NT GEMM: C[M,N] = sum_k A[m,k] * BT[n,k] (+ bias[m]); bf16 in, fp32 acc.
// Tiles 128x128x32, 256 threads = 4 waves in 2x2, each wave 64x64 via 4x4 MFMA 16x16x32.
// M,N multiples of 128; K multiple of 32. Grid (M/128, N/128, batch).
// ---------------------------------------------------------------------------
template <typename OutT, bool HAS_BIAS>
__global__ __launch_bounds__(256)
void gemm_nt(const u16* __restrict__ A, long strideA,
             const u16* __restrict__ BT, long strideBT,
             OutT* __restrict__ C, long strideC,
             const float* __restrict__ bias,
             int M, int N, int K) {
    __shared__ u16 As[128][40];  // +8 pad
    __shared__ u16 Bs[128][40];

    const int t  = threadIdx.x;
    const int m0 = blockIdx.x * 128;
    const int n0 = blockIdx.y * 128;
    const int b  = blockIdx.z;
    const u16* Ab = A  + (size_t)b * strideA;
    const u16* Bb = BT + (size_t)b * strideBT;

    const int srow = t >> 1;          // 0..127 staging row
    const int skg  = (t & 1) * 8;     // k-subgroup 0 or 8 (plus +16 for 2nd chunk)

    const int lane = t & 63;
    const int w    = t >> 6;
    const int wm   = (w & 1) * 64;
    const int wn   = (w >> 1) * 64;
    const int q    = lane >> 4;       // quad 0..3
    const int ln   = lane & 15;

    facc acc[4][4];
    for (int i = 0; i < 4; ++i)
        for (int j = 0; j < 4; ++j)
            acc[i][j] = (facc)0.0f;

    const int nK = K >> 5;
    for (int kt = 0; kt < nK; ++kt) {
        const int k0 = kt << 5;
        {   // stage A tile (128x32) and B tile (128x32), row-major [row][k]
            const u16* srcA = Ab + (size_t)(m0 + srow) * K + (k0 + skg);
            uint4 a0 = *reinterpret_cast<const uint4*>(srcA);
            uint4 a1 = *reinterpret_cast<const uint4*>(srcA + 16);
            *reinterpret_cast<uint4*>(&As[srow][skg])      = a0;
            *reinterpret_cast<uint4*>(&As[srow][skg + 16]) = a1;
            const u16* srcB = Bb + (size_t)(n0 + srow) * K + (k0 + skg);
            uint4 b0 = *reinterpret_cast<const uint4*>(srcB);
            uint4 b1 = *reinterpret_cast<const uint4*>(srcB + 16);
            *reinterpret_cast<uint4*>(&Bs[srow][skg])      = b0;
            *reinterpret_cast<uint4*>(&Bs[srow][skg + 16]) = b1;
        }
        __syncthreads();
        bfrag af[4], bfr[4];
        for (int mt = 0; mt < 4; ++mt)
            af[mt] = *reinterpret_cast<const bfrag*>(&As[wm + mt * 16 + ln][q * 8]);
        for (int nt = 0; nt < 4; ++nt)
            bfr[nt] = *reinterpret_cast<const bfrag*>(&Bs[wn + nt * 16 + ln][q * 8]);
        for (int mt = 0; mt < 4; ++mt)
            for (int nt = 0; nt < 4; ++nt)
                acc[mt][nt] = __builtin_amdgcn_mfma_f32_16x16x32_bf16(af[mt], bfr[nt], acc[mt][nt], 0, 0, 0);
        __syncthreads();
    }

    // epilogue: C/D layout col=lane&15, row=quad*4+r
    OutT* Cb = C + (size_t)b * strideC;
    for (int mt = 0; mt < 4; ++mt) {
        const int rbase = m0 + wm + mt * 16 + q * 4;
        for (int nt = 0; nt < 4; ++nt) {
            const int col = n0 + wn + nt * 16 + ln;
            for (int r = 0; r < 4; ++r) {
                float v = acc[mt][nt][r];
                if (HAS_BIAS) v += bias[rbase + r];
                store_out(&Cb[(size_t)(rbase + r) * N + col], v);
            }
        }
    }
}

// ---------------------------------------------------------------------------
// 2x2 maxpool: Y (bc,64,64) bf16 -> out (bc,32,32) bf16. total = B*1024*1024
// ---------------------------------------------------------------------------
__global__ void maxpool_k(const u16* __restrict__ Y, u16* __restrict__ out, int total) {
    int idx = blockIdx.x * blockDim.x + threadIdx.x;
    if (idx >= total) return;
    int x  = idx & 31;
    int y  = (idx >> 5) & 31;
    int bc = idx >> 10;
    const u16* p = Y + (size_t)bc * 4096 + (size_t)(2 * y) * 64 + 2 * x;
    float a = bf2f(p[0]), b = bf2f(p[1]), c = bf2f(p[64]), d = bf2f(p[65]);
    out[idx] = f2bf(fmaxf(fmaxf(a, b), fmaxf(c, d)));
}

// ---------------------------------------------------------------------------
// Row-wise relu + L2-normalize (axis=q): fm fp32 (rows x 1024) -> M bf16.
// One block (256 thr) per row.
// ---------------------------------------------------------------------------
__global__ void norm_k(const float* __restrict__ fm, u16* __restrict__ Mout) {
    __shared__ float red[4];
    const long row = blockIdx.x;
    const float* p = fm + row * 1024;
    const int t = threadIdx.x;
    float vals[4];
    float s = 0.f;
    for (int i = 0; i < 4; ++i) {
        float v = p[t + 256 * i];
        v = fmaxf(v, 0.f);
        vals[i] = v;
        s += v * v;
    }
    for (int off = 32; off; off >>= 1) s += __shfl_down(s, off, 64);
    if ((t & 63) == 0) red[t >> 6] = s;
    __syncthreads();
    float total = red[0] + red[1] + red[2] + red[3];
    float inv = 1.0f / sqrtf(total + 1e-6f);
    u16* o = Mout + row * 1024;
    for (int i = 0; i < 4; ++i) o[t + 256 * i] = f2bf(vals[i] * inv);
}

// ---------------------------------------------------------------------------
// Bilinear x2 upsample (align_corners): V fp32 (b*256, 32,32) -> out fp32 (b*256, 64,64)
// ---------------------------------------------------------------------------
__global__ void upsample_k(const float* __restrict__ V, float* __restrict__ out, int total) {
    int idx = blockIdx.x * blockDim.x + threadIdx.x;
    if (idx >= total) return;
    int X  = idx & 63;
    int Y  = (idx >> 6) & 63;
    long bo = idx >> 12;
    const float* p = V + bo * 1024;
    const float sc = 31.0f / 63.0f;
    float ys = Y * sc;
    float xs = X * sc;
    int y0 = (int)ys; int x0 = (int)xs;
    int y1 = y0 + 1; if (y1 > 31) y1 = 31;
    int x1 = x0 + 1; if (x1 > 31) x1 = 31;
    float ty = ys - y0, tx = xs - x0;
    float v00 = p[y0 * 32 + x0], v01 = p[y0 * 32 + x1];
    float v10 = p[y1 * 32 + x0], v11 = p[y1 * 32 + x1];
    float r = (1.f - ty) * ((1.f - tx) * v00 + tx * v01) + ty * ((1.f - tx) * v10 + tx * v11);
    out[idx] = r;
}

// ---------------------------------------------------------------------------
extern "C" void kernel_launch(void* const* d_in, const int* in_sizes, int n_in,
                              void* d_out, int out_size, void* d_ws, size_t ws_size,
                              hipStream_t stream) {
    const float* xa      = (const float*)d_in[0];   // (8,256,64,64)
    const float* xb      = (const float*)d_in[1];
    const float* conv_w  = (const float*)d_in[2];   // (1024,256)
    const float* conv_b  = (const float*)d_in[3];   // (1024,)
    const float* We      = (const float*)d_in[4];   // (1024,1024)
    const float* We2     = (const float*)d_in[5];   // (1024,1024)
    const float* conv2_w = (const float*)d_in[6];   // (256,1024)
    const float* conv2_b = (const float*)d_in[7];   // (256,)
    float* out = (float*)d_out;
    char* ws = (char*)d_ws;

    const long S1M = 1024L * 1024;      // per-batch elems of a 1024x1024 matrix
    const long SX  = 256L * 4096;       // per-batch elems of xa / xaT

    const long MiB = 1048576;
    // workspace layout (byte offsets) — peak ~149 MiB, heavy aliasing:
    u16*   Y   = (u16*)(ws + 0);             // [0,64M)  conv output, dead after pool
    float* FM  = (float*)(ws + 0);           // [0,32M)  fm fp32 (Y dead)
    u16*   Mb  = (u16*)(ws + 32 * MiB);      // [32M,48M)
    u16*   MT  = (u16*)(ws + 48 * MiB);      // [48M,64M)
    u16*   Z   = (u16*)(ws + 0);             // [0,16M)  (FM dead after norm)
    float* V   = (float*)(ws + 16 * MiB);    // [16M,24M) fp32
    u16*   XT  = (u16*)(ws + 64 * MiB);      // [64M,80M) xaT staging / later T1
    u16*   T1  = XT;
    u16*   FA  = (u16*)(ws + 80 * MiB);
    u16*   FB  = (u16*)(ws + 96 * MiB);
    u16*   FAT = (u16*)(ws + 112 * MiB);
    u16*   FBT = (u16*)(ws + 128 * MiB);
    u16*   CW  = (u16*)(ws + 144 * MiB);                 // 1024x256  bf16
    u16*   WE  = (u16*)(ws + 144 * MiB + 524288);        // 1024x1024
    u16*   WE2 = (u16*)(ws + 144 * MiB + 2621440);       // 1024x1024
    u16*   C2W = (u16*)(ws + 144 * MiB + 4718592);       // 256x1024

    const dim3 tb64(64, 8);

    // ---- convert weights fp32 -> bf16 ----
    cvt_k<<<1024, 256, 0, stream>>>(conv_w, CW, 262144);
    cvt_k<<<4096, 256, 0, stream>>>(We, WE, 1048576);
    cvt_k<<<4096, 256, 0, stream>>>(We2, WE2, 1048576);
    cvt_k<<<1024, 256, 0, stream>>>(conv2_w, C2W, 262144);

    // ---- feature extraction: fa = pool(conv(xa)), fb = pool(conv(xb)) ----
    transpose_k<float><<<dim3(64, 4, 8), tb64, 0, stream>>>(xa, XT, 256, 4096, SX, SX);
    gemm_nt<u16, true><<<dim3(8, 32, 8), 256, 0, stream>>>(CW, 0, XT, SX, Y, 1024L * 4096, conv_b, 1024, 4096, 256);
    maxpool_k<<<32768, 256, 0, stream>>>(Y, FA, 8 * 1024 * 1024);

    transpose_k<float><<<dim3(64, 4, 8), tb64, 0, stream>>>(xb, XT, 256, 4096, SX, SX);
    gemm_nt<u16, true><<<dim3(8, 32, 8), 256, 0, stream>>>(CW, 0, XT, SX, Y, 1024L * 4096, conv_b, 1024, 4096, 256);
    maxpool_k<<<32768, 256, 0, stream>>>(Y, FB, 8 * 1024 * 1024);

    transpose_k<u16><<<dim3(16, 16, 8), tb64, 0, stream>>>(FA, FAT, 1024, 1024, S1M, S1M);
    transpose_k<u16><<<dim3(16, 16, 8), tb64, 0, stream>>>(FB, FBT, 1024, 1024, S1M, S1M);

    // ---- path A: fm = (fb^T We^T) fa ; Mab ; en_a ----
    gemm_nt<u16, false><<<dim3(8, 8, 8), 256, 0, stream>>>(FBT, S1M, WE, 0, T1, S1M, nullptr, 1024, 1024, 1024);
    gemm_nt<float, false><<<dim3(8, 8, 8), 256, 0, stream>>>(T1, S1M, FAT, S1M, FM, S1M, nullptr, 1024, 1024, 1024);
    norm_k<<<8192, 256, 0, stream>>>(FM, Mb);
    transpose_k<u16><<<dim3(16, 16, 8), tb64, 0, stream>>>(Mb, MT, 1024, 1024, S1M, S1M);
    gemm_nt<u16, false><<<dim3(8, 8, 8), 256, 0, stream>>>(FA, S1M, MT, S1M, Z, S1M, nullptr, 1024, 1024, 1024);
    gemm_nt<float, true><<<dim3(2, 8, 8), 256, 0, stream>>>(C2W, 0, Z, S1M, V, 256L * 1024, conv2_b, 256, 1024, 1024);
    upsample_k<<<32768, 256, 0, stream>>>(V, out, 8 * 256 * 64 * 64);

    // ---- path B: fm2 = (fa^T We2^T) fb ; Mba ; en_b ----
    gemm_nt<u16, false><<<dim3(8, 8, 8), 256, 0, stream>>>(FAT, S1M, WE2, 0, T1, S1M, nullptr, 1024, 1024, 1024);
    gemm_nt<float, false><<<dim3(8, 8, 8), 256, 0, stream>>>(T1, S1M, FBT, S1M, FM, S1M, nullptr, 1024, 1024, 1024);
    norm_k<<<8192, 256, 0, stream>>>(FM, Mb);
    transpose_k<u16><<<dim3(16, 16, 8), tb64, 0, stream>>>(Mb, MT, 1024, 1024, S1M, S1M);
    gemm_nt<u16, false><<<dim3(8, 8, 8), 256, 0, stream>>>(FB, S1M, MT, S1M, Z, S1M, nullptr, 1024, 1024, 1024);
    gemm_nt<float, true><<<dim3(2, 8, 8), 256, 0, stream>>>(C2W, 0, Z, S1M, V, 256L * 1024, conv2_b, 256, 1024, 1024);
    upsample_k<<<32768, 256, 0, stream>>>(V, out + 8388608, 8 * 256 * 64 * 64);
}

// Round 3
// 536.430 us; speedup vs baseline: 1.1020x; 1.1020x over previous
//
#include <hip/hip_runtime.h>

typedef unsigned short u16;
typedef short bfrag __attribute__((ext_vector_type(8)));   // 8 bf16 (4 VGPRs) for MFMA A/B
typedef float facc  __attribute__((ext_vector_type(4)));   // 4 fp32 accumulator

__device__ __forceinline__ float bf2f(u16 u) {
    union { unsigned int i; float f; } v; v.i = ((unsigned int)u) << 16; return v.f;
}
__device__ __forceinline__ u16 f2bf(float f) {
    union { float f; unsigned int i; } v; v.f = f;
    unsigned int r = v.i + 0x7FFFu + ((v.i >> 16) & 1u);
    return (u16)(r >> 16);
}

__device__ __forceinline__ u16 ld_bf(const float* p) { return f2bf(*p); }
__device__ __forceinline__ u16 ld_bf(const u16* p)   { return *p; }

__device__ __forceinline__ void store_out(u16* p, float v)   { *p = f2bf(v); }
__device__ __forceinline__ void store_out(float* p, float v) { *p = v; }

// async global->LDS, 16B per lane; LDS dest = wave-uniform base + lane*16
__device__ __forceinline__ void gl2lds16(const u16* g, char* l) {
    __builtin_amdgcn_global_load_lds(
        (const __attribute__((address_space(1))) unsigned int*)g,
        (__attribute__((address_space(3))) unsigned int*)l,
        16, 0, 0);
}

// ---------------------------------------------------------------------------
// fp32 -> bf16 elementwise convert (for weight matrices)
// ---------------------------------------------------------------------------
__global__ void cvt_k(const float* __restrict__ src, u16* __restrict__ dst, int n) {
    int i = blockIdx.x * blockDim.x + threadIdx.x;
    if (i < n) dst[i] = f2bf(src[i]);
}

// ---------------------------------------------------------------------------
// Transpose (+ optional fp32->bf16): dst[C][R] = src[R][C], per batch.
// Grid (C/64, R/64, B), block (64,8)
// ---------------------------------------------------------------------------
template <typename SrcT>
__global__ void transpose_k(const SrcT* __restrict__ src, u16* __restrict__ dst,
                            int R, int C, long sStride, long dStride) {
    __shared__ u16 tile[64][65];
    const int b  = blockIdx.z;
    const int c0 = blockIdx.x * 64;
    const int r0 = blockIdx.y * 64;
    const int x  = threadIdx.x;   // 0..63
    const int y0 = threadIdx.y;   // 0..7
    const SrcT* s = src + (size_t)b * sStride;
    for (int i = 0; i < 8; ++i) {
        int r = y0 + i * 8;
        tile[r][x] = ld_bf(&s[(size_t)(r0 + r) * C + c0 + x]);
    }
    __syncthreads();
    u16* d = dst + (size_t)b * dStride;
    for (int i = 0; i < 8; ++i) {
        int c = y0 + i * 8;
        d[(size_t)(c0 + c) * R + r0 + x] = tile[x][c];
    }
}

// ---------------------------------------------------------------------------
// NT GEMM, m97-style staging: C[M,N] = sum_k A[m,k]*BT[n,k] (+bias[m]); bf16 in.
// 128x128x32 tiles, 256 thr = 4 waves 2x2, unpadded LDS, global_load_lds w=16.
// MODE: 0 = plain, 1 = +bias, 2 = +bias + fused 2x2 maxpool (conv1; N-tile = one
//       image row pair; pooled out is 1024-wide per batch, pooled row = blockIdx.y).
// ---------------------------------------------------------------------------
template <typename OutT, int MODE>
__global__ __launch_bounds__(256)
void gemm_nt(const u16* __restrict__ A, long strideA,
             const u16* __restrict__ BT, long strideBT,
             OutT* __restrict__ C, long strideC,
             const float* __restrict__ bias,
             int M, int N, int K) {
    constexpr bool HAS_BIAS = (MODE >= 1);
    constexpr bool POOL     = (MODE == 2);
    constexpr int  SMEM_SZ  = POOL ? 33792 : 16384;  // pool: 2x 128x33 fp32
    __shared__ __align__(16) char smem[SMEM_SZ];
    char* AsB = smem;            // A tile: 128 rows x 64B (32 bf16), unpadded
    char* BsB = smem + 8192;     // B tile

    const int t  = threadIdx.x;
    const int m0 = blockIdx.x * 128;
    const int n0 = blockIdx.y * 128;
    const int b  = blockIdx.z;
    const u16* Ab = A  + (size_t)b * strideA;
    const u16* Bb = BT + (size_t)b * strideBT;

    const int lane = t & 63;
    const int w    = t >> 6;
    const int wm   = (w & 1) * 64;
    const int wn   = (w >> 1) * 64;
    const int q    = lane >> 4;       // quad 0..3 -> k-chunk
    const int ln   = lane & 15;

    // staging slots: slot s (16B) holds row s>>2, k-chunk s&3 (8 bf16)
    const int s0 = w * 128 + lane;    // wave-contiguous: base w*2048 + lane*16
    const int s1 = s0 + 64;
    const int r0s = s0 >> 2, c0s = (s0 & 3) * 8;
    const int r1s = s1 >> 2, c1s = (s1 & 3) * 8;

    facc acc[4][4];
    for (int i = 0; i < 4; ++i)
        for (int j = 0; j < 4; ++j)
            acc[i][j] = (facc)0.0f;

    const int nK = K >> 5;
    for (int kt = 0; kt < nK; ++kt) {
        const int k0 = kt << 5;
        gl2lds16(Ab + (size_t)(m0 + r0s) * K + (k0 + c0s), AsB + s0 * 16);
        gl2lds16(Ab + (size_t)(m0 + r1s) * K + (k0 + c1s), AsB + s1 * 16);
        gl2lds16(Bb + (size_t)(n0 + r0s) * K + (k0 + c0s), BsB + s0 * 16);
        gl2lds16(Bb + (size_t)(n0 + r1s) * K + (k0 + c1s), BsB + s1 * 16);
        __syncthreads();
        bfrag af[4], bfr[4];
        for (int mt = 0; mt < 4; ++mt)
            af[mt] = *reinterpret_cast<const bfrag*>(AsB + (wm + mt * 16 + ln) * 64 + q * 16);
        for (int nt = 0; nt < 4; ++nt)
            bfr[nt] = *reinterpret_cast<const bfrag*>(BsB + (wn + nt * 16 + ln) * 64 + q * 16);
        for (int mt = 0; mt < 4; ++mt)
            for (int nt = 0; nt < 4; ++nt)
                acc[mt][nt] = __builtin_amdgcn_mfma_f32_16x16x32_bf16(af[mt], bfr[nt], acc[mt][nt], 0, 0, 0);
        __syncthreads();
    }

    OutT* Cb = C + (size_t)b * strideC;

    if (POOL) {
        // N-tile cols 0..63 = image row 2*by, 64..127 = row 2*by+1 (64-wide image)
        float* pool0 = (float*)smem;             // [128][33] fp32, row 2*by
        float* pool1 = (float*)(smem + 16896);   // row 2*by+1
        float* pb = (w >> 1) ? pool1 : pool0;    // this wave's image row half
        for (int mt = 0; mt < 4; ++mt) {
            for (int nt = 0; nt < 4; ++nt) {
                for (int r = 0; r < 4; ++r) {
                    int ch = wm + mt * 16 + q * 4 + r;           // local channel
                    float v = acc[mt][nt][r] + bias[m0 + ch];
                    float vm = fmaxf(v, __shfl_xor(v, 1, 64));   // horizontal pair
                    if (!(ln & 1))
                        pb[ch * 33 + ((nt * 16 + ln) >> 1)] = vm;
                }
            }
        }
        __syncthreads();
        for (int i = 0; i < 16; ++i) {
            int idx = t + i * 256;               // 0..4095 = 128ch x 32xp
            int ch = idx >> 5, xp = idx & 31;
            float v = fmaxf(pool0[ch * 33 + xp], pool1[ch * 33 + xp]);
            store_out(&Cb[(size_t)(m0 + ch) * 1024 + blockIdx.y * 32 + xp], v);
        }
    } else {
        // epilogue: C/D layout col=lane&15, row=quad*4+r
        for (int mt = 0; mt < 4; ++mt) {
            const int rbase = m0 + wm + mt * 16 + q * 4;
            for (int nt = 0; nt < 4; ++nt) {
                const int col = n0 + wn + nt * 16 + ln;
                for (int r = 0; r < 4; ++r) {
                    float v = acc[mt][nt][r];
                    if (HAS_BIAS) v += bias[rbase + r];
                    store_out(&Cb[(size_t)(rbase + r) * N + col], v);
                }
            }
        }
    }
}

// ---------------------------------------------------------------------------
// Row-wise relu + L2-normalize over last axis: fm bf16 (rows x 1024) -> M bf16.
// One block (256 thr) per row; vectorized 4x u16.
// ---------------------------------------------------------------------------
__global__ void norm_k(const u16* __restrict__ fm, u16* __restrict__ Mout) {
    __shared__ float red[4];
    const long row = blockIdx.x;
    const u16* p = fm + row * 1024;
    const int t = threadIdx.x;
    uint2 raw = *reinterpret_cast<const uint2*>(p + t * 4);
    float v0 = fmaxf(bf2f((u16)(raw.x & 0xFFFF)), 0.f);
    float v1 = fmaxf(bf2f((u16)(raw.x >> 16)), 0.f);
    float v2 = fmaxf(bf2f((u16)(raw.y & 0xFFFF)), 0.f);
    float v3 = fmaxf(bf2f((u16)(raw.y >> 16)), 0.f);
    float s = v0 * v0 + v1 * v1 + v2 * v2 + v3 * v3;
    for (int off = 32; off; off >>= 1) s += __shfl_down(s, off, 64);
    if ((t & 63) == 0) red[t >> 6] = s;
    __syncthreads();
    float total = red[0] + red[1] + red[2] + red[3];
    float inv = 1.0f / sqrtf(total + 1e-6f);
    uint2 o;
    o.x = (unsigned)f2bf(v0 * inv) | ((unsigned)f2bf(v1 * inv) << 16);
    o.y = (unsigned)f2bf(v2 * inv) | ((unsigned)f2bf(v3 * inv) << 16);
    *reinterpret_cast<uint2*>(Mout + row * 1024 + t * 4) = o;
}

// ---------------------------------------------------------------------------
// Bilinear x2 upsample (align_corners): V fp32 (bo,32,32) -> out fp32 (bo,64,64)
// ---------------------------------------------------------------------------
__global__ void upsample_k(const float* __restrict__ V, float* __restrict__ out, int total) {
    int idx = blockIdx.x * blockDim.x + threadIdx.x;
    if (idx >= total) return;
    int X  = idx & 63;
    int Y  = (idx >> 6) & 63;
    long bo = idx >> 12;
    const float* p = V + bo * 1024;
    const float sc = 31.0f / 63.0f;
    float ys = Y * sc;
    float xs = X * sc;
    int y0 = (int)ys; int x0 = (int)xs;
    int y1 = y0 + 1; if (y1 > 31) y1 = 31;
    int x1 = x0 + 1; if (x1 > 31) x1 = 31;
    float ty = ys - y0, tx = xs - x0;
    float v00 = p[y0 * 32 + x0], v01 = p[y0 * 32 + x1];
    float v10 = p[y1 * 32 + x0], v11 = p[y1 * 32 + x1];
    float r = (1.f - ty) * ((1.f - tx) * v00 + tx * v01) + ty * ((1.f - tx) * v10 + tx * v11);
    out[idx] = r;
}

// ---------------------------------------------------------------------------
extern "C" void kernel_launch(void* const* d_in, const int* in_sizes, int n_in,
                              void* d_out, int out_size, void* d_ws, size_t ws_size,
                              hipStream_t stream) {
    const float* xa      = (const float*)d_in[0];   // (8,256,64,64)
    const float* xb      = (const float*)d_in[1];
    const float* conv_w  = (const float*)d_in[2];   // (1024,256)
    const float* conv_b  = (const float*)d_in[3];   // (1024,)
    const float* We      = (const float*)d_in[4];   // (1024,1024)
    const float* We2     = (const float*)d_in[5];   // (1024,1024)
    const float* conv2_w = (const float*)d_in[6];   // (256,1024)
    const float* conv2_b = (const float*)d_in[7];   // (256,)
    float* out = (float*)d_out;
    char* ws = (char*)d_ws;

    const long S1M = 1024L * 1024;      // per-batch elems of a 1024x1024 matrix
    const long SX  = 256L * 4096;       // per-batch elems of xaT
    const long MiB = 1048576;

    // workspace layout (byte offsets), peak ~133 MiB:
    u16*   XT  = (u16*)(ws + 0);             // [0,32M)  xaT+xbT (16 batches), dead after conv
    u16*   T1  = (u16*)(ws + 0);             // [0,16M)  per path
    u16*   FM  = (u16*)(ws + 16 * MiB);      // [16M,32M) fm bf16
    u16*   Z   = (u16*)(ws + 0);             // [0,16M)  (T1 dead)
    float* V   = (float*)(ws + 16 * MiB);    // [16M,24M) conv2 out fp32 (FM dead)
    u16*   FA  = (u16*)(ws + 32 * MiB);      // [32M,48M) pooled feats a
    u16*   FB  = (u16*)(ws + 48 * MiB);      // [48M,64M) pooled feats b (contig w/ FA)
    u16*   FAT = (u16*)(ws + 64 * MiB);
    u16*   FBT = (u16*)(ws + 80 * MiB);
    u16*   Mb  = (u16*)(ws + 96 * MiB);      // per path
    u16*   MT  = (u16*)(ws + 112 * MiB);     // per path
    u16*   CW  = (u16*)(ws + 128 * MiB);                 // 1024x256 bf16
    u16*   WE  = (u16*)(ws + 128 * MiB + 524288);        // 1024x1024
    u16*   WE2 = (u16*)(ws + 128 * MiB + 2621440);       // 1024x1024
    u16*   C2W = (u16*)(ws + 128 * MiB + 4718592);       // 256x1024

    const dim3 tb64(64, 8);

    // ---- convert weights fp32 -> bf16 ----
    cvt_k<<<1024, 256, 0, stream>>>(conv_w, CW, 262144);
    cvt_k<<<4096, 256, 0, stream>>>(We, WE, 1048576);
    cvt_k<<<4096, 256, 0, stream>>>(We2, WE2, 1048576);
    cvt_k<<<1024, 256, 0, stream>>>(conv2_w, C2W, 262144);

    // ---- fa = pool(conv(xa)), fb = pool(conv(xb)); one batch-16 GEMM ----
    transpose_k<float><<<dim3(64, 4, 8), tb64, 0, stream>>>(xa, XT, 256, 4096, SX, SX);
    transpose_k<float><<<dim3(64, 4, 8), tb64, 0, stream>>>(xb, XT + 8 * SX, 256, 4096, SX, SX);
    gemm_nt<u16, 2><<<dim3(8, 32, 16), 256, 0, stream>>>(CW, 0, XT, SX, FA, S1M, conv_b, 1024, 4096, 256);

    transpose_k<u16><<<dim3(16, 16, 8), tb64, 0, stream>>>(FA, FAT, 1024, 1024, S1M, S1M);
    transpose_k<u16><<<dim3(16, 16, 8), tb64, 0, stream>>>(FB, FBT, 1024, 1024, S1M, S1M);

    // ---- path A: fm = (fb^T We^T) fa ; Mab ; en_a ----
    gemm_nt<u16, 0><<<dim3(8, 8, 8), 256, 0, stream>>>(FBT, S1M, WE, 0, T1, S1M, nullptr, 1024, 1024, 1024);
    gemm_nt<u16, 0><<<dim3(8, 8, 8), 256, 0, stream>>>(T1, S1M, FAT, S1M, FM, S1M, nullptr, 1024, 1024, 1024);
    norm_k<<<8192, 256, 0, stream>>>(FM, Mb);
    transpose_k<u16><<<dim3(16, 16, 8), tb64, 0, stream>>>(Mb, MT, 1024, 1024, S1M, S1M);
    gemm_nt<u16, 0><<<dim3(8, 8, 8), 256, 0, stream>>>(FA, S1M, MT, S1M, Z, S1M, nullptr, 1024, 1024, 1024);
    gemm_nt<float, 1><<<dim3(2, 8, 8), 256, 0, stream>>>(C2W, 0, Z, S1M, V, 256L * 1024, conv2_b, 256, 1024, 1024);
    upsample_k<<<32768, 256, 0, stream>>>(V, out, 8 * 256 * 64 * 64);

    // ---- path B: fm2 = (fa^T We2^T) fb ; Mba ; en_b ----
    gemm_nt<u16, 0><<<dim3(8, 8, 8), 256, 0, stream>>>(FAT, S1M, WE2, 0, T1, S1M, nullptr, 1024, 1024, 1024);
    gemm_nt<u16, 0><<<dim3(8, 8, 8), 256, 0, stream>>>(T1, S1M, FBT, S1M, FM, S1M, nullptr, 1024, 1024, 1024);
    norm_k<<<8192, 256, 0, stream>>>(FM, Mb);
    transpose_k<u16><<<dim3(16, 16, 8), tb64, 0, stream>>>(Mb, MT, 1024, 1024, S1M, S1M);
    gemm_nt<u16, 0><<<dim3(8, 8, 8), 256, 0, stream>>>(FB, S1M, MT, S1M, Z, S1M, nullptr, 1024, 1024, 1024);
    gemm_nt<float, 1><<<dim3(2, 8, 8), 256, 0, stream>>>(C2W, 0, Z, S1M, V, 256L * 1024, conv2_b, 256, 1024, 1024);
    upsample_k<<<32768, 256, 0, stream>>>(V, out + 8388608, 8 * 256 * 64 * 64);
}

// Round 4
// 461.307 us; speedup vs baseline: 1.2814x; 1.1628x over previous
//
#include <hip/hip_runtime.h>

typedef unsigned short u16;
typedef short bfrag __attribute__((ext_vector_type(8)));   // 8 bf16 (4 VGPRs) for MFMA A/B
typedef float facc  __attribute__((ext_vector_type(4)));   // 4 fp32 accumulator

__device__ __forceinline__ float bf2f(u16 u) {
    union { unsigned int i; float f; } v; v.i = ((unsigned int)u) << 16; return v.f;
}
__device__ __forceinline__ u16 f2bf(float f) {
    union { float f; unsigned int i; } v; v.f = f;
    unsigned int r = v.i + 0x7FFFu + ((v.i >> 16) & 1u);
    return (u16)(r >> 16);
}

__device__ __forceinline__ u16 ld_bf(const float* p) { return f2bf(*p); }
__device__ __forceinline__ u16 ld_bf(const u16* p)   { return *p; }

__device__ __forceinline__ void store_out(u16* p, float v)   { *p = f2bf(v); }
__device__ __forceinline__ void store_out(float* p, float v) { *p = v; }

// async global->LDS, 16B per lane; LDS dest = wave-uniform base + lane*16
__device__ __forceinline__ void gl2lds16(const u16* g, char* l) {
    __builtin_amdgcn_global_load_lds(
        (const __attribute__((address_space(1))) unsigned int*)g,
        (__attribute__((address_space(3))) unsigned int*)l,
        16, 0, 0);
}

// ---------------------------------------------------------------------------
// fp32 -> bf16 convert for the 4 weight tensors in one launch
// ---------------------------------------------------------------------------
__global__ void cvt4_k(const float* __restrict__ s0, u16* __restrict__ d0,
                       const float* __restrict__ s1, u16* __restrict__ d1,
                       const float* __restrict__ s2, u16* __restrict__ d2,
                       const float* __restrict__ s3, u16* __restrict__ d3) {
    int i = blockIdx.x * blockDim.x + threadIdx.x;
    if (i < 262144)        d0[i] = f2bf(s0[i]);
    else if (i < 1310720)  d1[i - 262144] = f2bf(s1[i - 262144]);
    else if (i < 2359296)  d2[i - 1310720] = f2bf(s2[i - 1310720]);
    else                   d3[i - 2359296] = f2bf(s3[i - 2359296]);
}

// ---------------------------------------------------------------------------
// Input transpose + fp32->bf16: xa/xb (b,256,4096) -> XT (16b, 4096, 256)
// Grid (64, 4, 16), block (64,8). z<8 -> xa, z>=8 -> xb.
// ---------------------------------------------------------------------------
__global__ void transpose_in_k(const float* __restrict__ srcA,
                               const float* __restrict__ srcB,
                               u16* __restrict__ dst) {
    __shared__ u16 tile[64][65];
    const long SX = 1048576;  // 256*4096
    const int z  = blockIdx.z;
    const int c0 = blockIdx.x * 64;   // spatial
    const int r0 = blockIdx.y * 64;   // channel
    const int x  = threadIdx.x;
    const int y0 = threadIdx.y;
    const float* s = (z < 8 ? srcA : srcB) + (size_t)(z & 7) * SX;
    for (int i = 0; i < 8; ++i) {
        int r = y0 + i * 8;
        tile[r][x] = f2bf(s[(size_t)(r0 + r) * 4096 + c0 + x]);
    }
    __syncthreads();
    u16* d = dst + (size_t)z * SX;
    for (int i = 0; i < 8; ++i) {
        int c = y0 + i * 8;
        d[(size_t)(c0 + c) * 256 + r0 + x] = tile[x][c];
    }
}

// ---------------------------------------------------------------------------
// Generic bf16 transpose: dst[C][R] = src[R][C] per batch. Grid (C/64,R/64,B)
// ---------------------------------------------------------------------------
__global__ void transpose_k(const u16* __restrict__ src, u16* __restrict__ dst,
                            int R, int C, long sStride, long dStride) {
    __shared__ u16 tile[64][65];
    const int b  = blockIdx.z;
    const int c0 = blockIdx.x * 64;
    const int r0 = blockIdx.y * 64;
    const int x  = threadIdx.x;
    const int y0 = threadIdx.y;
    const u16* s = src + (size_t)b * sStride;
    for (int i = 0; i < 8; ++i) {
        int r = y0 + i * 8;
        tile[r][x] = s[(size_t)(r0 + r) * C + c0 + x];
    }
    __syncthreads();
    u16* d = dst + (size_t)b * dStride;
    for (int i = 0; i < 8; ++i) {
        int c = y0 + i * 8;
        d[(size_t)(c0 + c) * R + r0 + x] = tile[x][c];
    }
}

// ---------------------------------------------------------------------------
// NT GEMM with XCD swizzle: C[M,N] = sum_k A[m,k]*BT[n,k]; bf16 in, fp32 acc.
// 128x128x32 tiles, 256 thr, global_load_lds w=16 staging.
// MODE: 0 plain, 1 +bias, 2 +bias +fused 2x2 maxpool writing pooled FA (ch-major
//       via C) AND pooled FAT (spatial-major via CT).
// PAIRED: batches 0-7 use A0/B0, 8-15 use A1/B1 (local b&7); else A0/B0 + full b.
// ---------------------------------------------------------------------------
template <typename OutT, int MODE, bool PAIRED>
__global__ __launch_bounds__(256)
void gemm_nt(const u16* __restrict__ A0, const u16* __restrict__ A1, long strideA,
             const u16* __restrict__ B0, const u16* __restrict__ B1, long strideBT,
             OutT* __restrict__ C, long strideC, u16* __restrict__ CT,
             const float* __restrict__ bias, int M, int N, int K) {
    constexpr bool HAS_BIAS = (MODE >= 1);
    constexpr bool POOL     = (MODE == 2);
    constexpr int  SMEM_SZ  = POOL ? 33792 : 16384;  // pool: 2x 128x33 fp32
    __shared__ __align__(16) char smem[SMEM_SZ];
    char* AsB = smem;            // A tile: 128 rows x 64B (32 bf16), unpadded
    char* BsB = smem + 8192;

    // XCD-aware swizzle: id%8 (XCD selector) -> contiguous chunk of (y,z) with all x,
    // so B-tiles are reused within one XCD's L2. Requires total blocks % 8 == 0.
    const int gx = gridDim.x, gy = gridDim.y;
    long id = blockIdx.x + (long)gx * (blockIdx.y + (long)gy * blockIdx.z);
    long total = (long)gx * gy * gridDim.z;
    long nid = (id & 7) * (total >> 3) + (id >> 3);
    const int bx = (int)(nid % gx);
    long rr = nid / gx;
    const int by = (int)(rr % gy);
    const int b  = (int)(rr / gy);

    const int m0 = bx * 128;
    const int n0 = by * 128;

    const u16* Ab; const u16* Bb;
    if (PAIRED) {
        const int bl = b & 7;
        Ab = (b < 8 ? A0 : A1) + (size_t)bl * strideA;
        Bb = (b < 8 ? B0 : B1) + (size_t)bl * strideBT;
    } else {
        Ab = A0 + (size_t)b * strideA;
        Bb = B0 + (size_t)b * strideBT;
    }

    const int t    = threadIdx.x;
    const int lane = t & 63;
    const int w    = t >> 6;
    const int wm   = (w & 1) * 64;
    const int wn   = (w >> 1) * 64;
    const int q    = lane >> 4;
    const int ln   = lane & 15;

    // staging slots: slot s (16B) holds row s>>2, k-chunk s&3
    const int s0 = w * 128 + lane;
    const int s1 = s0 + 64;
    const int r0s = s0 >> 2, c0s = (s0 & 3) * 8;
    const int r1s = s1 >> 2, c1s = (s1 & 3) * 8;

    facc acc[4][4];
    for (int i = 0; i < 4; ++i)
        for (int j = 0; j < 4; ++j)
            acc[i][j] = (facc)0.0f;

    const int nK = K >> 5;
    for (int kt = 0; kt < nK; ++kt) {
        const int k0 = kt << 5;
        gl2lds16(Ab + (size_t)(m0 + r0s) * K + (k0 + c0s), AsB + s0 * 16);
        gl2lds16(Ab + (size_t)(m0 + r1s) * K + (k0 + c1s), AsB + s1 * 16);
        gl2lds16(Bb + (size_t)(n0 + r0s) * K + (k0 + c0s), BsB + s0 * 16);
        gl2lds16(Bb + (size_t)(n0 + r1s) * K + (k0 + c1s), BsB + s1 * 16);
        __syncthreads();
        bfrag af[4], bfr[4];
        for (int mt = 0; mt < 4; ++mt)
            af[mt] = *reinterpret_cast<const bfrag*>(AsB + (wm + mt * 16 + ln) * 64 + q * 16);
        for (int nt = 0; nt < 4; ++nt)
            bfr[nt] = *reinterpret_cast<const bfrag*>(BsB + (wn + nt * 16 + ln) * 64 + q * 16);
        for (int mt = 0; mt < 4; ++mt)
            for (int nt = 0; nt < 4; ++nt)
                acc[mt][nt] = __builtin_amdgcn_mfma_f32_16x16x32_bf16(af[mt], bfr[nt], acc[mt][nt], 0, 0, 0);
        __syncthreads();
    }

    OutT* Cb = C + (size_t)b * strideC;

    if (POOL) {
        // N-tile = image rows 2*by (cols 0..63) and 2*by+1 (cols 64..127)
        float* pool0 = (float*)smem;             // [128][33] fp32
        float* pool1 = (float*)(smem + 16896);
        float* pb = (w >> 1) ? pool1 : pool0;
        for (int mt = 0; mt < 4; ++mt) {
            for (int nt = 0; nt < 4; ++nt) {
                for (int r = 0; r < 4; ++r) {
                    int ch = wm + mt * 16 + q * 4 + r;
                    float v = acc[mt][nt][r] + bias[m0 + ch];
                    float vm = fmaxf(v, __shfl_xor(v, 1, 64));   // horizontal pair
                    if (!(ln & 1))
                        pb[ch * 33 + ((nt * 16 + ln) >> 1)] = vm;
                }
            }
        }
        __syncthreads();
        // pass 1: vertical max -> FA (ch-major, uint = 2 xp), stash final in pool0
        u16* Cp = (u16*)Cb;
        for (int i = 0; i < 8; ++i) {
            int idx = t + i * 256;               // 2048 = 128ch x 16 xp-pairs
            int ch = idx >> 4, xpp = (idx & 15) * 2;
            float v0 = fmaxf(pool0[ch * 33 + xpp],     pool1[ch * 33 + xpp]);
            float v1 = fmaxf(pool0[ch * 33 + xpp + 1], pool1[ch * 33 + xpp + 1]);
            unsigned pk = (unsigned)f2bf(v0) | ((unsigned)f2bf(v1) << 16);
            *reinterpret_cast<unsigned*>(&Cp[(size_t)(m0 + ch) * 1024 + by * 32 + xpp]) = pk;
            pool0[ch * 33 + xpp] = v0; pool0[ch * 33 + xpp + 1] = v1;
        }
        __syncthreads();
        // pass 2: transposed copy -> FAT (spatial-major, uint = 2 ch)
        u16* CTb = CT + (size_t)b * strideC;
        for (int i = 0; i < 8; ++i) {
            int idx = t + i * 256;               // 2048 = 32 xp x 64 ch-pairs
            int ch2 = (idx & 63) * 2, xp = idx >> 6;
            unsigned pk = (unsigned)f2bf(pool0[ch2 * 33 + xp]) |
                          ((unsigned)f2bf(pool0[(ch2 + 1) * 33 + xp]) << 16);
            *reinterpret_cast<unsigned*>(&CTb[(size_t)(by * 32 + xp) * 1024 + m0 + ch2]) = pk;
        }
    } else {
        // epilogue: C/D layout col=lane&15, row=quad*4+r
        for (int mt = 0; mt < 4; ++mt) {
            const int rbase = m0 + wm + mt * 16 + q * 4;
            for (int nt = 0; nt < 4; ++nt) {
                const int col = n0 + wn + nt * 16 + ln;
                for (int r = 0; r < 4; ++r) {
                    float v = acc[mt][nt][r];
                    if (HAS_BIAS) v += bias[rbase + r];
                    store_out(&Cb[(size_t)(rbase + r) * N + col], v);
                }
            }
        }
    }
}

// ---------------------------------------------------------------------------
// Row-wise relu + L2-normalize: fm bf16 (rows x 1024) -> M bf16. 1 block/row.
// ---------------------------------------------------------------------------
__global__ void norm_k(const u16* __restrict__ fm, u16* __restrict__ Mout) {
    __shared__ float red[4];
    const long row = blockIdx.x;
    const u16* p = fm + row * 1024;
    const int t = threadIdx.x;
    uint2 raw = *reinterpret_cast<const uint2*>(p + t * 4);
    float v0 = fmaxf(bf2f((u16)(raw.x & 0xFFFF)), 0.f);
    float v1 = fmaxf(bf2f((u16)(raw.x >> 16)), 0.f);
    float v2 = fmaxf(bf2f((u16)(raw.y & 0xFFFF)), 0.f);
    float v3 = fmaxf(bf2f((u16)(raw.y >> 16)), 0.f);
    float s = v0 * v0 + v1 * v1 + v2 * v2 + v3 * v3;
    for (int off = 32; off; off >>= 1) s += __shfl_down(s, off, 64);
    if ((t & 63) == 0) red[t >> 6] = s;
    __syncthreads();
    float total = red[0] + red[1] + red[2] + red[3];
    float inv = 1.0f / sqrtf(total + 1e-6f);
    uint2 o;
    o.x = (unsigned)f2bf(v0 * inv) | ((unsigned)f2bf(v1 * inv) << 16);
    o.y = (unsigned)f2bf(v2 * inv) | ((unsigned)f2bf(v3 * inv) << 16);
    *reinterpret_cast<uint2*>(Mout + row * 1024 + t * 4) = o;
}

// ---------------------------------------------------------------------------
// Bilinear x2 upsample (align_corners): V fp32 (4096 ch-imgs, 32,32) -> out fp32
// ---------------------------------------------------------------------------
__global__ void upsample_k(const float* __restrict__ V, float* __restrict__ out, int total) {
    int idx = blockIdx.x * blockDim.x + threadIdx.x;
    if (idx >= total) return;
    int X  = idx & 63;
    int Y  = (idx >> 6) & 63;
    long bo = idx >> 12;
    const float* p = V + bo * 1024;
    const float sc = 31.0f / 63.0f;
    float ys = Y * sc;
    float xs = X * sc;
    int y0 = (int)ys; int x0 = (int)xs;
    int y1 = y0 + 1; if (y1 > 31) y1 = 31;
    int x1 = x0 + 1; if (x1 > 31) x1 = 31;
    float ty = ys - y0, tx = xs - x0;
    float v00 = p[y0 * 32 + x0], v01 = p[y0 * 32 + x1];
    float v10 = p[y1 * 32 + x0], v11 = p[y1 * 32 + x1];
    out[idx] = (1.f - ty) * ((1.f - tx) * v00 + tx * v01) + ty * ((1.f - tx) * v10 + tx * v11);
}

// ---------------------------------------------------------------------------
extern "C" void kernel_launch(void* const* d_in, const int* in_sizes, int n_in,
                              void* d_out, int out_size, void* d_ws, size_t ws_size,
                              hipStream_t stream) {
    const float* xa      = (const float*)d_in[0];   // (8,256,64,64)
    const float* xb      = (const float*)d_in[1];
    const float* conv_w  = (const float*)d_in[2];   // (1024,256)
    const float* conv_b  = (const float*)d_in[3];   // (1024,)
    const float* We      = (const float*)d_in[4];   // (1024,1024)
    const float* We2     = (const float*)d_in[5];   // (1024,1024)
    const float* conv2_w = (const float*)d_in[6];   // (256,1024)
    const float* conv2_b = (const float*)d_in[7];   // (256,)
    float* out = (float*)d_out;
    char* ws = (char*)d_ws;

    const long S1M = 1048576;           // 1024x1024 elems (= per-batch stride everywhere)
    const long MiB = 1048576;

    // workspace (byte offsets), peak 133 MiB:
    // [0,32)   XT -> T1 -> Mb -> Z         (sequential lifetimes)
    // [32,64)  FA (0-7) / FB (8-15)        pooled features, ch-major
    // [64,96)  FAT (0-7) / FBT (8-15)      pooled features, spatial-major; later V at [64,80)
    // [96,128) FM -> MT
    // [128,133) weights bf16
    u16*   XT  = (u16*)(ws + 0);
    u16*   T1  = (u16*)(ws + 0);
    u16*   Mb  = (u16*)(ws + 0);
    u16*   Z   = (u16*)(ws + 0);
    u16*   FA  = (u16*)(ws + 32 * MiB);
    u16*   FB  = (u16*)(ws + 48 * MiB);
    u16*   FAT = (u16*)(ws + 64 * MiB);
    u16*   FBT = (u16*)(ws + 80 * MiB);
    float* V   = (float*)(ws + 64 * MiB);
    u16*   FM  = (u16*)(ws + 96 * MiB);
    u16*   MT  = (u16*)(ws + 96 * MiB);
    u16*   CW  = (u16*)(ws + 128 * MiB);
    u16*   WE  = (u16*)(ws + 128 * MiB + 524288);
    u16*   WE2 = (u16*)(ws + 128 * MiB + 2621440);
    u16*   C2W = (u16*)(ws + 128 * MiB + 4718592);

    const dim3 tb64(64, 8);

    // 1. weights fp32 -> bf16
    cvt4_k<<<10240, 256, 0, stream>>>(conv_w, CW, We, WE, We2, WE2, conv2_w, C2W);

    // 2. input transpose+convert: XT[z][spatial][ch], z 0-7 = xa, 8-15 = xb
    transpose_in_k<<<dim3(64, 4, 16), tb64, 0, stream>>>(xa, xb, XT);

    // 3. conv1 + bias + 2x2 maxpool, writes FA/FB (ch-major) + FAT/FBT (spatial-major)
    gemm_nt<u16, 2, false><<<dim3(8, 32, 16), 256, 0, stream>>>(
        CW, CW, 0, XT, XT, S1M, FA, S1M, FAT, conv_b, 1024, 4096, 256);

    // 4. T1: path a (0-7) = FBT . We^T ; path b (8-15) = FAT . We2^T
    gemm_nt<u16, 0, true><<<dim3(8, 8, 16), 256, 0, stream>>>(
        FBT, FAT, S1M, WE, WE2, 0, T1, S1M, nullptr, nullptr, 1024, 1024, 1024);

    // 5. fm: path a = T1 . FAT^T ; path b = T1 . FBT^T
    gemm_nt<u16, 0, true><<<dim3(8, 8, 16), 256, 0, stream>>>(
        T1, T1 + 8 * S1M, S1M, FAT, FBT, S1M, FM, S1M, nullptr, nullptr, 1024, 1024, 1024);

    // 6. relu + row L2-norm
    norm_k<<<16384, 256, 0, stream>>>(FM, Mb);

    // 7. M^T
    transpose_k<<<dim3(16, 16, 16), tb64, 0, stream>>>(Mb, MT, 1024, 1024, S1M, S1M);

    // 8. en: path a = FA . MT^T ; path b = FB . MT^T  -> Z (ch x spatial)
    gemm_nt<u16, 0, true><<<dim3(8, 8, 16), 256, 0, stream>>>(
        FA, FB, S1M, MT, MT + 8 * S1M, S1M, Z, S1M, nullptr, nullptr, 1024, 1024, 1024);

    // 9. conv2 + bias (fp32 out)
    gemm_nt<float, 1, false><<<dim3(2, 8, 16), 256, 0, stream>>>(
        C2W, C2W, 0, Z, Z, S1M, V, 256L * 1024, nullptr, conv2_b, 256, 1024, 1024);

    // 10. bilinear x2 upsample -> d_out (both paths, V batch order matches out)
    upsample_k<<<65536, 256, 0, stream>>>(V, out, 16 * 256 * 4096);
}

// Round 5
// 421.324 us; speedup vs baseline: 1.4030x; 1.0949x over previous
//
#include <hip/hip_runtime.h>

typedef unsigned short u16;
typedef short bfrag __attribute__((ext_vector_type(8)));   // 8 bf16 (4 VGPRs) for MFMA A/B
typedef float facc  __attribute__((ext_vector_type(4)));   // 4 fp32 accumulator

__device__ __forceinline__ float bf2f(u16 u) {
    union { unsigned int i; float f; } v; v.i = ((unsigned int)u) << 16; return v.f;
}
__device__ __forceinline__ u16 f2bf(float f) {
    union { float f; unsigned int i; } v; v.f = f;
    unsigned int r = v.i + 0x7FFFu + ((v.i >> 16) & 1u);
    return (u16)(r >> 16);
}

__device__ __forceinline__ void store_out(u16* p, float v)   { *p = f2bf(v); }
__device__ __forceinline__ void store_out(float* p, float v) { *p = v; }

// async global->LDS, 16B per lane; LDS dest = wave-uniform base + lane*16
__device__ __forceinline__ void gl2lds16(const u16* g, char* l) {
    __builtin_amdgcn_global_load_lds(
        (const __attribute__((address_space(1))) unsigned int*)g,
        (__attribute__((address_space(3))) unsigned int*)l,
        16, 0, 0);
}

// ---------------------------------------------------------------------------
// fp32 -> bf16 convert for the 4 weight tensors in one launch
// ---------------------------------------------------------------------------
__global__ void cvt4_k(const float* __restrict__ s0, u16* __restrict__ d0,
                       const float* __restrict__ s1, u16* __restrict__ d1,
                       const float* __restrict__ s2, u16* __restrict__ d2,
                       const float* __restrict__ s3, u16* __restrict__ d3) {
    int i = blockIdx.x * blockDim.x + threadIdx.x;
    if (i < 262144)        d0[i] = f2bf(s0[i]);
    else if (i < 1310720)  d1[i - 262144] = f2bf(s1[i - 262144]);
    else if (i < 2359296)  d2[i - 1310720] = f2bf(s2[i - 1310720]);
    else                   d3[i - 2359296] = f2bf(s3[i - 2359296]);
}

// ---------------------------------------------------------------------------
// Input transpose + fp32->bf16: xa/xb (b,256,4096) -> XT (16b, 4096, 256)
// Grid (64, 4, 16), block (64,8). z<8 -> xa, z>=8 -> xb.
// ---------------------------------------------------------------------------
__global__ void transpose_in_k(const float* __restrict__ srcA,
                               const float* __restrict__ srcB,
                               u16* __restrict__ dst) {
    __shared__ u16 tile[64][65];
    const long SX = 1048576;  // 256*4096
    const int z  = blockIdx.z;
    const int c0 = blockIdx.x * 64;   // spatial
    const int r0 = blockIdx.y * 64;   // channel
    const int x  = threadIdx.x;
    const int y0 = threadIdx.y;
    const float* s = (z < 8 ? srcA : srcB) + (size_t)(z & 7) * SX;
    for (int i = 0; i < 8; ++i) {
        int r = y0 + i * 8;
        tile[r][x] = f2bf(s[(size_t)(r0 + r) * 4096 + c0 + x]);
    }
    __syncthreads();
    u16* d = dst + (size_t)z * SX;
    for (int i = 0; i < 8; ++i) {
        int c = y0 + i * 8;
        d[(size_t)(c0 + c) * 256 + r0 + x] = tile[x][c];
    }
}

// ---------------------------------------------------------------------------
// NT GEMM, XCD swizzle, BK=64 (two BK=32 sub-tiles lo/hi per barrier round):
// C[M,N] = sum_k A[m,k]*BT[n,k]; bf16 in, fp32 acc. 128x128 tiles, 256 thr.
// MODE: 0 plain bf16 out (LDS-packed dwordx4 stores), 1 +bias fp32 out,
//       2 +bias +fused 2x2 maxpool writing FA (ch-major) + FAT (spatial-major).
// PAIRED: batches 0-7 use A0/B0, 8-15 use A1/B1 (local b&7).
// K must be a multiple of 64.
// ---------------------------------------------------------------------------
template <typename OutT, int MODE, bool PAIRED>
__global__ __launch_bounds__(256)
void gemm_nt(const u16* __restrict__ A0, const u16* __restrict__ A1, long strideA,
             const u16* __restrict__ B0, const u16* __restrict__ B1, long strideBT,
             OutT* __restrict__ C, long strideC, u16* __restrict__ CT,
             const float* __restrict__ bias, int M, int N, int K) {
    constexpr bool POOL    = (MODE == 2);
    constexpr int  SMEM_SZ = POOL ? 33792 : 32768;
    __shared__ __align__(16) char smem[SMEM_SZ];
    char* As = smem;              // A: lo [0,8K), hi [8K,16K); 128 rows x 64B each
    char* Bs = smem + 16384;      // B: lo, hi

    // XCD-aware swizzle: id%8 (XCD selector) -> contiguous chunk of (y,z) with all x.
    const int gx = gridDim.x, gy = gridDim.y;
    long id = blockIdx.x + (long)gx * (blockIdx.y + (long)gy * blockIdx.z);
    long total = (long)gx * gy * gridDim.z;
    long nid = (id & 7) * (total >> 3) + (id >> 3);
    const int bx = (int)(nid % gx);
    long rr = nid / gx;
    const int by = (int)(rr % gy);
    const int b  = (int)(rr / gy);

    const int m0 = bx * 128;
    const int n0 = by * 128;

    const u16* Ab; const u16* Bb;
    if (PAIRED) {
        const int bl = b & 7;
        Ab = (b < 8 ? A0 : A1) + (size_t)bl * strideA;
        Bb = (b < 8 ? B0 : B1) + (size_t)bl * strideBT;
    } else {
        Ab = A0 + (size_t)b * strideA;
        Bb = B0 + (size_t)b * strideBT;
    }

    const int t    = threadIdx.x;
    const int lane = t & 63;
    const int w    = t >> 6;
    const int wm   = (w & 1) * 64;
    const int wn   = (w >> 1) * 64;
    const int q    = lane >> 4;
    const int ln   = lane & 15;

    // staging slots within an 8 KiB sub-tile (512 slots of 16B):
    // slot s: row = s>>2, k-chunk = s&3 (8 bf16 each)
    const int s0 = w * 64 + lane;     // [0,256)
    const int s1 = s0 + 256;          // [256,512)
    const int r0s = s0 >> 2, c0s = (s0 & 3) * 8;
    const int r1s = s1 >> 2, c1s = (s1 & 3) * 8;

    const u16* pA0 = Ab + (size_t)(m0 + r0s) * K + c0s;
    const u16* pA1 = Ab + (size_t)(m0 + r1s) * K + c1s;
    const u16* pB0 = Bb + (size_t)(n0 + r0s) * K + c0s;
    const u16* pB1 = Bb + (size_t)(n0 + r1s) * K + c1s;

    facc acc[4][4];
    for (int i = 0; i < 4; ++i)
        for (int j = 0; j < 4; ++j)
            acc[i][j] = (facc)0.0f;

    const int nK = K >> 6;
    for (int kt = 0; kt < nK; ++kt) {
        const int k0 = kt << 6;
        gl2lds16(pA0 + k0,      As + s0 * 16);
        gl2lds16(pA1 + k0,      As + s1 * 16);
        gl2lds16(pA0 + k0 + 32, As + 8192 + s0 * 16);
        gl2lds16(pA1 + k0 + 32, As + 8192 + s1 * 16);
        gl2lds16(pB0 + k0,      Bs + s0 * 16);
        gl2lds16(pB1 + k0,      Bs + s1 * 16);
        gl2lds16(pB0 + k0 + 32, Bs + 8192 + s0 * 16);
        gl2lds16(pB1 + k0 + 32, Bs + 8192 + s1 * 16);
        __syncthreads();
        for (int j = 0; j < 2; ++j) {
            const char* Aj = As + j * 8192;
            const char* Bj = Bs + j * 8192;
            bfrag af[4], bfr[4];
            for (int mt = 0; mt < 4; ++mt)
                af[mt] = *reinterpret_cast<const bfrag*>(Aj + (wm + mt * 16 + ln) * 64 + q * 16);
            for (int nt = 0; nt < 4; ++nt)
                bfr[nt] = *reinterpret_cast<const bfrag*>(Bj + (wn + nt * 16 + ln) * 64 + q * 16);
            for (int mt = 0; mt < 4; ++mt)
                for (int nt = 0; nt < 4; ++nt)
                    acc[mt][nt] = __builtin_amdgcn_mfma_f32_16x16x32_bf16(af[mt], bfr[nt], acc[mt][nt], 0, 0, 0);
        }
        __syncthreads();
    }

    if (POOL) {
        // N-tile = image rows 2*by (cols 0..63) and 2*by+1 (cols 64..127)
        u16* Cp  = (u16*)C + (size_t)b * strideC;
        float* pool0 = (float*)smem;             // [128ch][33] fp32
        float* pool1 = (float*)(smem + 16896);
        float* pb = (w >> 1) ? pool1 : pool0;
        for (int mt = 0; mt < 4; ++mt) {
            for (int nt = 0; nt < 4; ++nt) {
                for (int r = 0; r < 4; ++r) {
                    int ch = wm + mt * 16 + q * 4 + r;
                    float v = acc[mt][nt][r] + bias[m0 + ch];
                    float vm = fmaxf(v, __shfl_xor(v, 1, 64));   // horizontal pair
                    if (!(ln & 1))
                        pb[ch * 33 + ((nt * 16 + ln) >> 1)] = vm;
                }
            }
        }
        __syncthreads();
        // pass 1: vertical max -> FA (ch-major), stash final in pool0
        for (int i = 0; i < 8; ++i) {
            int idx = t + i * 256;               // 2048 = 128ch x 16 xp-pairs
            int ch = idx >> 4, xpp = (idx & 15) * 2;
            float v0 = fmaxf(pool0[ch * 33 + xpp],     pool1[ch * 33 + xpp]);
            float v1 = fmaxf(pool0[ch * 33 + xpp + 1], pool1[ch * 33 + xpp + 1]);
            unsigned pk = (unsigned)f2bf(v0) | ((unsigned)f2bf(v1) << 16);
            *reinterpret_cast<unsigned*>(&Cp[(size_t)(m0 + ch) * 1024 + by * 32 + xpp]) = pk;
            pool0[ch * 33 + xpp] = v0; pool0[ch * 33 + xpp + 1] = v1;
        }
        __syncthreads();
        // pass 2: transposed copy -> FAT (spatial-major)
        u16* CTb = CT + (size_t)b * strideC;
        for (int i = 0; i < 8; ++i) {
            int idx = t + i * 256;               // 2048 = 32 xp x 64 ch-pairs
            int ch2 = (idx & 63) * 2, xp = idx >> 6;
            unsigned pk = (unsigned)f2bf(pool0[ch2 * 33 + xp]) |
                          ((unsigned)f2bf(pool0[(ch2 + 1) * 33 + xp]) << 16);
            *reinterpret_cast<unsigned*>(&CTb[(size_t)(by * 32 + xp) * 1024 + m0 + ch2]) = pk;
        }
    } else if (MODE == 0) {
        // LDS-packed bf16 epilogue: dump 128x128 u16, re-read as uint4,
        // store 256B-contiguous segments.
        u16* Cb = (u16*)C + (size_t)b * strideC;
        u16* dump = (u16*)smem;
        for (int mt = 0; mt < 4; ++mt)
            for (int nt = 0; nt < 4; ++nt)
                for (int r = 0; r < 4; ++r)
                    dump[(wm + mt * 16 + q * 4 + r) * 128 + wn + nt * 16 + ln] = f2bf(acc[mt][nt][r]);
        __syncthreads();
        for (int i = 0; i < 8; ++i) {
            const int row = w * 32 + i * 4 + (lane >> 4);
            const uint4 v = *reinterpret_cast<const uint4*>(dump + row * 128 + (lane & 15) * 8);
            *reinterpret_cast<uint4*>(Cb + (size_t)(m0 + row) * N + n0 + (lane & 15) * 8) = v;
        }
    } else {
        // MODE 1: +bias, fp32 out (conv2; small grid)
        OutT* Cb = C + (size_t)b * strideC;
        for (int mt = 0; mt < 4; ++mt) {
            const int rbase = m0 + wm + mt * 16 + q * 4;
            for (int nt = 0; nt < 4; ++nt) {
                const int col = n0 + wn + nt * 16 + ln;
                for (int r = 0; r < 4; ++r)
                    store_out(&Cb[(size_t)(rbase + r) * N + col], acc[mt][nt][r] + bias[rbase + r]);
            }
        }
    }
}

// ---------------------------------------------------------------------------
// Row inverse-L2-norm of relu(fm): rinv[row] = 1/sqrt(sum relu(v)^2 + eps)
// One block (256 thr) per row of 1024.
// ---------------------------------------------------------------------------
__global__ void norm_rk(const u16* __restrict__ fm, float* __restrict__ rinv) {
    __shared__ float red[4];
    const long row = blockIdx.x;
    const u16* p = fm + row * 1024;
    const int t = threadIdx.x;
    uint2 raw = *reinterpret_cast<const uint2*>(p + t * 4);
    float v0 = fmaxf(bf2f((u16)(raw.x & 0xFFFF)), 0.f);
    float v1 = fmaxf(bf2f((u16)(raw.x >> 16)), 0.f);
    float v2 = fmaxf(bf2f((u16)(raw.y & 0xFFFF)), 0.f);
    float v3 = fmaxf(bf2f((u16)(raw.y >> 16)), 0.f);
    float s = v0 * v0 + v1 * v1 + v2 * v2 + v3 * v3;
    for (int off = 32; off; off >>= 1) s += __shfl_down(s, off, 64);
    if ((t & 63) == 0) red[t >> 6] = s;
    __syncthreads();
    if (t == 0)
        rinv[row] = 1.0f / sqrtf(red[0] + red[1] + red[2] + red[3] + 1e-6f);
}

// ---------------------------------------------------------------------------
// Fused relu+scale+transpose: dst[q][p] = relu(src[p][q]) * rinv[p], per batch.
// Grid (16,16,16), block (64,8).
// ---------------------------------------------------------------------------
__global__ void transpose_scale_k(const u16* __restrict__ src,
                                  const float* __restrict__ rinv,
                                  u16* __restrict__ dst) {
    __shared__ u16 tile[64][65];
    const long S = 1048576;
    const int b  = blockIdx.z;
    const int c0 = blockIdx.x * 64;   // q
    const int r0 = blockIdx.y * 64;   // p
    const int x  = threadIdx.x;
    const int y0 = threadIdx.y;
    const u16* s = src + (size_t)b * S;
    const float* rv = rinv + (size_t)b * 1024;
    for (int i = 0; i < 8; ++i) {
        int r = y0 + i * 8;
        float v = fmaxf(bf2f(s[(size_t)(r0 + r) * 1024 + c0 + x]), 0.f) * rv[r0 + r];
        tile[r][x] = f2bf(v);
    }
    __syncthreads();
    u16* d = dst + (size_t)b * S;
    for (int i = 0; i < 8; ++i) {
        int c = y0 + i * 8;
        d[(size_t)(c0 + c) * 1024 + r0 + x] = tile[x][c];
    }
}

// ---------------------------------------------------------------------------
// Bilinear x2 upsample (align_corners): V fp32 (4096 ch-imgs, 32,32) -> out fp32
// ---------------------------------------------------------------------------
__global__ void upsample_k(const float* __restrict__ V, float* __restrict__ out, int total) {
    int idx = blockIdx.x * blockDim.x + threadIdx.x;
    if (idx >= total) return;
    int X  = idx & 63;
    int Y  = (idx >> 6) & 63;
    long bo = idx >> 12;
    const float* p = V + bo * 1024;
    const float sc = 31.0f / 63.0f;
    float ys = Y * sc;
    float xs = X * sc;
    int y0 = (int)ys; int x0 = (int)xs;
    int y1 = y0 + 1; if (y1 > 31) y1 = 31;
    int x1 = x0 + 1; if (x1 > 31) x1 = 31;
    float ty = ys - y0, tx = xs - x0;
    float v00 = p[y0 * 32 + x0], v01 = p[y0 * 32 + x1];
    float v10 = p[y1 * 32 + x0], v11 = p[y1 * 32 + x1];
    out[idx] = (1.f - ty) * ((1.f - tx) * v00 + tx * v01) + ty * ((1.f - tx) * v10 + tx * v11);
}

// ---------------------------------------------------------------------------
extern "C" void kernel_launch(void* const* d_in, const int* in_sizes, int n_in,
                              void* d_out, int out_size, void* d_ws, size_t ws_size,
                              hipStream_t stream) {
    const float* xa      = (const float*)d_in[0];   // (8,256,64,64)
    const float* xb      = (const float*)d_in[1];
    const float* conv_w  = (const float*)d_in[2];   // (1024,256)
    const float* conv_b  = (const float*)d_in[3];   // (1024,)
    const float* We      = (const float*)d_in[4];   // (1024,1024)
    const float* We2     = (const float*)d_in[5];   // (1024,1024)
    const float* conv2_w = (const float*)d_in[6];   // (256,1024)
    const float* conv2_b = (const float*)d_in[7];   // (256,)
    float* out = (float*)d_out;
    char* ws = (char*)d_ws;

    const long S1M = 1048576;
    const long MiB = 1048576;

    // workspace (byte offsets), peak ~137 MiB:
    // [0,32)    XT -> T1 -> MT            (sequential lifetimes)
    // [32,64)   FA (0-7) / FB (8-15)      pooled features, ch-major
    // [64,96)   FAT/FBT; after step 5: V at [64,80)
    // [96,128)  FM -> Z
    // [128,..)  weights bf16 + rinv
    u16*   XT  = (u16*)(ws + 0);
    u16*   T1  = (u16*)(ws + 0);
    u16*   MT  = (u16*)(ws + 0);
    u16*   FA  = (u16*)(ws + 32 * MiB);
    u16*   FB  = (u16*)(ws + 48 * MiB);
    u16*   FAT = (u16*)(ws + 64 * MiB);
    u16*   FBT = (u16*)(ws + 80 * MiB);
    float* V   = (float*)(ws + 64 * MiB);
    u16*   FM  = (u16*)(ws + 96 * MiB);
    u16*   Z   = (u16*)(ws + 96 * MiB);
    u16*   CW  = (u16*)(ws + 128 * MiB);
    u16*   WE  = (u16*)(ws + 128 * MiB + 524288);
    u16*   WE2 = (u16*)(ws + 128 * MiB + 2621440);
    u16*   C2W = (u16*)(ws + 128 * MiB + 4718592);
    float* RIV = (float*)(ws + 128 * MiB + 5242880);   // 16x1024 fp32

    const dim3 tb64(64, 8);

    // 1. weights fp32 -> bf16
    cvt4_k<<<10240, 256, 0, stream>>>(conv_w, CW, We, WE, We2, WE2, conv2_w, C2W);

    // 2. input transpose+convert: XT[z][spatial][ch]
    transpose_in_k<<<dim3(64, 4, 16), tb64, 0, stream>>>(xa, xb, XT);

    // 3. conv1 + bias + 2x2 maxpool -> FA/FB (ch-major) + FAT/FBT (spatial-major)
    gemm_nt<u16, 2, false><<<dim3(8, 32, 16), 256, 0, stream>>>(
        CW, CW, 0, XT, XT, S1M, FA, S1M, FAT, conv_b, 1024, 4096, 256);

    // 4. T1: path a = FBT . We^T ; path b = FAT . We2^T
    gemm_nt<u16, 0, true><<<dim3(8, 8, 16), 256, 0, stream>>>(
        FBT, FAT, S1M, WE, WE2, 0, T1, S1M, nullptr, nullptr, 1024, 1024, 1024);

    // 5. fm: path a = T1 . FAT^T ; path b = T1 . FBT^T
    gemm_nt<u16, 0, true><<<dim3(8, 8, 16), 256, 0, stream>>>(
        T1, T1 + 8 * S1M, S1M, FAT, FBT, S1M, FM, S1M, nullptr, nullptr, 1024, 1024, 1024);

    // 6. row inverse norms of relu(fm)
    norm_rk<<<16384, 256, 0, stream>>>(FM, RIV);

    // 7. MT[q][p] = relu(fm[p][q]) * rinv[p]
    transpose_scale_k<<<dim3(16, 16, 16), tb64, 0, stream>>>(FM, RIV, MT);

    // 8. en: path a = FA . MT^T ; path b = FB . MT^T  -> Z (ch x spatial)
    gemm_nt<u16, 0, true><<<dim3(8, 8, 16), 256, 0, stream>>>(
        FA, FB, S1M, MT, MT + 8 * S1M, S1M, Z, S1M, nullptr, nullptr, 1024, 1024, 1024);

    // 9. conv2 + bias (fp32 out)
    gemm_nt<float, 1, false><<<dim3(2, 8, 16), 256, 0, stream>>>(
        C2W, C2W, 0, Z, Z, S1M, V, 256L * 1024, nullptr, conv2_b, 256, 1024, 1024);

    // 10. bilinear x2 upsample -> d_out
    upsample_k<<<65536, 256, 0, stream>>>(V, out, 16 * 256 * 4096);
}